// Round 14
// baseline (17097.600 us; speedup 1.0000x reference)
//
#include <hip/hip_runtime.h>
#include <hip/hip_bf16.h>

#define UNITS 1024
#define BATCH 128
#define SEQ   512
#define NWG   256
#define NTHR  1024

typedef short bf16x8 __attribute__((ext_vector_type(8)));
typedef float f32x4  __attribute__((ext_vector_type(4)));

// ---- fp32 <-> bf16 split helpers (RNE) ----
__device__ __forceinline__ unsigned short f2bf(float v) {
    union { float f; unsigned u; } x; x.f = v;
    unsigned r = x.u + 0x7fffu + ((x.u >> 16) & 1u);
    return (unsigned short)(r >> 16);
}
__device__ __forceinline__ float bf2f(unsigned short s) {
    union { unsigned u; float f; } x; x.u = ((unsigned)s) << 16;
    return x.f;
}
__device__ __forceinline__ float sigmf(float v) { return 1.0f / (1.0f + expf(-v)); }

// A: lane holds A[row=l&15][k=8*(l>>4)+j]; B: B[k=8*(l>>4)+j][col=l&15];
// D: D[row=4*(l>>4)+r][col=l&15]
__device__ __forceinline__ f32x4 mfma_plain(bf16x8 a, bf16x8 b, f32x4 c) {
    asm("v_mfma_f32_16x16x32_bf16 %0, %1, %2, %0" : "+v"(c) : "v"(a), "v"(b));
    return c;
}
// s_nop fused into the SAME asm: guaranteed wait states between a preceding VALU
// write of a/b/c and the MFMA read (hazard recognizer can't see inline asm).
__device__ __forceinline__ f32x4 mfma_guard(bf16x8 a, bf16x8 b, f32x4 c) {
    asm("s_nop 3\n\tv_mfma_f32_16x16x32_bf16 %0, %1, %2, %0" : "+v"(c) : "v"(a), "v"(b));
    return c;
}

// 8 consecutive f32 -> bf16x8 via v_cvt_pk_bf16_f32 (VALU)
__device__ __forceinline__ bf16x8 cvt8(const float* p) {
    float4 f0 = *(const float4*)p;
    float4 f1 = *(const float4*)(p + 4);
    union { unsigned u[4]; bf16x8 v; } r;
    asm("v_cvt_pk_bf16_f32 %0, %1, %2" : "=v"(r.u[0]) : "v"(f0.x), "v"(f0.y));
    asm("v_cvt_pk_bf16_f32 %0, %1, %2" : "=v"(r.u[1]) : "v"(f0.z), "v"(f0.w));
    asm("v_cvt_pk_bf16_f32 %0, %1, %2" : "=v"(r.u[2]) : "v"(f1.x), "v"(f1.y));
    asm("v_cvt_pk_bf16_f32 %0, %1, %2" : "=v"(r.u[3]) : "v"(f1.z), "v"(f1.w));
    return r.v;
}

// non-temporal f32 store: out is never re-read -> don't let it evict E from LLC
__device__ __forceinline__ void store_f32_nt(float* p, float v) {
    asm volatile("global_store_dword %0, %1, off nt" :: "v"(p), "v"(v) : "memory");
}

__device__ __forceinline__ void flag_store(unsigned* p, unsigned v) {
    __hip_atomic_store(p, v, __ATOMIC_RELAXED, __HIP_MEMORY_SCOPE_AGENT);
}
__device__ __forceinline__ unsigned flag_load(const unsigned* p) {
    return __hip_atomic_load(p, __ATOMIC_RELAXED, __HIP_MEMORY_SCOPE_AGENT);
}

// Hierarchical barrier. Release: wbl2 (dirty h/eb -> LLC) + tree flags.
// Acquire: ONE L2-invalidate per PHYSICAL XCD (elected via HW_REG_XCC_ID +
// atomicMax), everyone else L1-only -> preserves per-XCD L2 reuse of the
// h/eb broadcast (32 WGs share one LLC fetch instead of 32).
__device__ __forceinline__ void grid_barrier(unsigned tgt, int wg, int tid, int grp, int local,
                                             unsigned* xarr, unsigned* garr,
                                             unsigned* grel, unsigned* xlead,
                                             unsigned* xrel)
{
    __syncthreads();
    if (tid == 0) {
        __builtin_amdgcn_fence(__ATOMIC_RELEASE, "agent");  // dirty L2 -> LLC
        flag_store(&xarr[wg * 16], tgt);
    }
    if (local == 0) {                        // tree fan-in leader (logical group)
        if (tid < 32)
            while (flag_load(&xarr[(grp + 8 * tid) * 16]) < tgt)
                __builtin_amdgcn_s_sleep(1);
        __syncthreads();
        if (tid == 0) flag_store(&garr[grp * 16], tgt);
    }
    if (wg == 0) {                           // global leader
        if (tid < 8)
            while (flag_load(&garr[tid * 16]) < tgt)
                __builtin_amdgcn_s_sleep(1);
        __syncthreads();
        if (tid == 0) flag_store(grel, tgt);
    }
    if (tid == 0) {
        while (flag_load(grel) < tgt) __builtin_amdgcn_s_sleep(1);
        // per-physical-XCD single L2 invalidate (election), L1-inv for all
        unsigned px;
        asm volatile("s_getreg_b32 %0, hwreg(HW_REG_XCC_ID)" : "=s"(px));
        px &= 7;
        unsigned pre = __hip_atomic_fetch_max(&xlead[px * 16], tgt,
                                              __ATOMIC_RELAXED, __HIP_MEMORY_SCOPE_AGENT);
        if (pre < tgt) {
            asm volatile("buffer_inv sc1\n\ts_waitcnt vmcnt(0)" ::: "memory"); // L1+L2
            flag_store(&xrel[px * 16], tgt);
        } else {
            while (flag_load(&xrel[px * 16]) < tgt) __builtin_amdgcn_s_sleep(1);
            asm volatile("buffer_inv sc0\n\ts_waitcnt vmcnt(0)" ::: "memory"); // L1 only
        }
    }
    __syncthreads();
}

// ============ single persistent kernel, 256 WGs x 1024 thr (16 waves/CU) ============
// Each WG owns 4 h-cols = 16 gate-cols (gate-interleaved: cc = 4*hcol + g).
// K-split: wave w<8 = rows w*16..+15, K[0,512); wave w+8 = same rows, K[512,1024).
// Per step: acc = h@Wfused (+eg in low wave), ne = ebuf@Wcat_hi; partials reduced
// via LDS; low waves do LSTM epilogue; high waves produce ebuf[(t+2)%3].
__global__ void __launch_bounds__(1024, 1)
lstm_all(const int* __restrict__ x, const float* __restrict__ E,
         const float* __restrict__ Wh, const float* __restrict__ bvec,
         const float* __restrict__ Wf, const float* __restrict__ Wi,
         const float* __restrict__ Wc, const float* __restrict__ Wo,
         const float* __restrict__ bfv, const float* __restrict__ biv,
         const float* __restrict__ bcv, const float* __restrict__ bov,
         unsigned* __restrict__ xarr, unsigned* __restrict__ garr,
         unsigned* __restrict__ grel, unsigned* __restrict__ xlead,
         unsigned* __restrict__ xrel,
         unsigned short* __restrict__ h_hi0, unsigned short* __restrict__ h_lo0,
         unsigned short* __restrict__ h_hi1, unsigned short* __restrict__ h_lo1,
         unsigned short* __restrict__ eb,    // 3 slots of [128][1024] bf16
         float* __restrict__ out)
{
    __shared__ unsigned short lwf_h[16 * 1032];   // 33 KB Wfused tile hi (2064 B rows)
    __shared__ unsigned short lwf_l[16 * 1032];   // 33 KB Wfused tile lo
    __shared__ unsigned short lwc_h[16 * 1032];   // 33 KB Wcat tile hi
    __shared__ unsigned short lwc_l[16 * 1032];   // 33 KB Wcat tile lo (S3 only)
    __shared__ __align__(16) float scA[8][16][20];  // 10 KB acc partials / G epilogue
    __shared__ __align__(16) float scN[8][16][20];  // 10 KB ne partials
    __shared__ float bgl[16];

    const int wg = blockIdx.x, tid = threadIdx.x;
    const int wave = tid >> 6, lane = tid & 63;
    const int l16 = lane & 15, lk = lane >> 4;
    const int wlow = wave & 7;               // row-group
    const int khalf = wave >> 3;             // 0 = K[0,512), 1 = K[512,1024)

    // logical column ownership (also the barrier-tree grouping)
    const int grp = wg & 7, local = wg >> 3;
    const int hcb = grp * 128 + local * 4;   // 4 h-cols
    const int gcb = hcb * 4;                 // 16 gate-cols

    const int kh   = khalf * 512;
    const int bbW  = l16 * 2064 + kh * 2 + lk * 16;  // weight-LDS byte offset
    const int bbW0 = l16 * 2064 + lk * 16;           // full-K variant (S3)
    const char* qfh = (const char*)lwf_h;
    const char* qfl = (const char*)lwf_l;
    const char* qch = (const char*)lwc_h;
    const char* qcl = (const char*)lwc_l;

    // ======== S1: build Wcat^T dual tile from f32 gate weights ========
    for (int idx = tid; idx < 16 * 1024; idx += NTHR) {
        int i = idx >> 10, k = idx & 1023;
        int cc = gcb + i;
        int j = cc >> 2, g = cc & 3;
        const float* W = (g == 0) ? Wf : (g == 1) ? Wi : (g == 2) ? Wc : Wo;
        float v = W[k * UNITS + j];
        unsigned short hi = f2bf(v);
        lwc_h[i * 1032 + k] = hi;
        lwc_l[i * 1032 + k] = f2bf(v - bf2f(hi));
    }
    __syncthreads();

    // ======== S2: bgl[i] = sum_k bvec[k] * Wcat[k][gcb+i] ========
    {
        int i = tid >> 6, seg = tid & 63;    // 16 cols x 64 segments of 16
        float s = 0.0f;
        #pragma unroll 4
        for (int k = seg * 16; k < seg * 16 + 16; ++k)
            s += bvec[k] * (bf2f(lwc_h[i * 1032 + k]) + bf2f(lwc_l[i * 1032 + k]));
        ((float*)scA)[i * 64 + seg] = s;
    }
    __syncthreads();
    if (tid < 16) {
        float s = 0.0f;
        #pragma unroll
        for (int q = 0; q < 64; ++q) s += ((float*)scA)[tid * 64 + q];
        bgl[tid] = s;
    }
    __syncthreads();

    // ======== S3: Wfused tile = Wh @ Wcat_tile (dual x dual, 3 products) ========
    for (int rt = wave; rt < 64; rt += 16) {
        const int kb = rt * 16;
        const float* pa = Wh + (size_t)(kb + l16) * UNITS + lk * 8;
        f32x4 acc = {0, 0, 0, 0};
        for (int kt = 0; kt < 32; ++kt) {
            float4 w0 = *(const float4*)pa;
            float4 w1 = *(const float4*)(pa + 4);
            pa += 32;
            union { unsigned short u[8]; bf16x8 v; } ah, al;
            float wv[8] = {w0.x, w0.y, w0.z, w0.w, w1.x, w1.y, w1.z, w1.w};
            #pragma unroll
            for (int j = 0; j < 8; ++j) {
                ah.u[j] = f2bf(wv[j]);
                al.u[j] = f2bf(wv[j] - bf2f(ah.u[j]));
            }
            bf16x8 bh = *(const bf16x8*)(qch + bbW0 + kt * 64);
            bf16x8 bl = *(const bf16x8*)(qcl + bbW0 + kt * 64);
            acc = mfma_guard(ah.v, bh, acc);
            acc = mfma_guard(ah.v, bl, acc);
            acc = mfma_guard(al.v, bh, acc);
        }
        asm volatile("s_nop 7\n\ts_nop 7" : "+v"(acc));
        #pragma unroll
        for (int r = 0; r < 4; ++r) {
            float v = acc[r];
            unsigned short hi = f2bf(v);
            int o = l16 * 1032 + kb + 4 * lk + r;
            lwf_h[o] = hi;
            lwf_l[o] = f2bf(v - bf2f(hi));
        }
    }
    __syncthreads();

    // ---- per-thread epilogue statics ----
    const int row_l = lane >> 2;             // 0..15
    const int jj    = lane & 3;              // h-col within WG
    const int col   = hcb + jj;
    const float bf_r = bfv[col] + bgl[4 * jj + 0];
    const float bi_r = biv[col] + bgl[4 * jj + 1];
    const float bc_r = bcv[col] + bgl[4 * jj + 2];
    const float bo_r = bov[col] + bgl[4 * jj + 3];
    float hreg = 0.0f;
    const int R0 = wlow * 16;

    unsigned short* cur_hi = h_hi0; unsigned short* cur_lo = h_lo0;
    unsigned short* nxt_hi = h_hi1; unsigned short* nxt_lo = h_lo1;
    const size_t EBS = (size_t)BATCH * UNITS;     // one ebuf slot

    // ---- prologue: produce ebuf slot0 (tokens t=0) and slot1 (tokens t=1) ----
    {
        int q = tid;
        if (q < 64) {
            int tok = x[(wg >> 1) * SEQ + 0];
            const float* ps = E + (size_t)tok * UNITS + (wg & 1) * 512 + q * 8;
            *(bf16x8*)(eb + (wg >> 1) * UNITS + (wg & 1) * 512 + q * 8) = cvt8(ps);
        } else if (q < 128) {
            int qq = q - 64;
            int tok = x[(wg >> 1) * SEQ + 1];
            const float* ps = E + (size_t)tok * UNITS + (wg & 1) * 512 + qq * 8;
            *(bf16x8*)(eb + EBS + (wg >> 1) * UNITS + (wg & 1) * 512 + qq * 8) = cvt8(ps);
        }
    }
    grid_barrier(1u, wg, tid, grp, local, xarr, garr, grel, xlead, xrel);

    // ---- prologue ne: eg for t=0 from ebuf slot0 (K-split, LDS reduce) ----
    f32x4 eg = {0, 0, 0, 0};
    {
        const unsigned short* pe = eb + (R0 + l16) * UNITS + kh + lk * 8;
        f32x4 ne = {0, 0, 0, 0};
        #pragma unroll 4
        for (int kt = 0; kt < 16; ++kt) {
            bf16x8 e0 = *(const bf16x8*)pe; pe += 32;
            bf16x8 ch = *(const bf16x8*)(qch + bbW + kt * 64);
            ne = mfma_plain(e0, ch, ne);
        }
        asm volatile("s_nop 7\n\ts_nop 7" : "+v"(ne));
        if (khalf) {
            #pragma unroll
            for (int r = 0; r < 4; ++r) scN[wlow][lk * 4 + r][l16] = ne[r];
        }
        __syncthreads();
        if (!khalf) {
            #pragma unroll
            for (int r = 0; r < 4; ++r) eg[r] = ne[r] + scN[wlow][lk * 4 + r][l16];
        }
    }

    #pragma unroll 1
    for (int t = 0; t < SEQ; ++t) {
        const unsigned short* ebr = eb + ((t + 1) % 3) * EBS;   // tokens t+1
        const unsigned short* pe  = ebr + (R0 + l16) * UNITS + kh + lk * 8;
        const unsigned short* ph0 = cur_hi + (R0 + l16) * UNITS + kh + lk * 8;
        const unsigned short* pl0 = cur_lo + (R0 + l16) * UNITS + kh + lk * 8;

        f32x4 acc = khalf ? f32x4{0, 0, 0, 0} : eg;   // eg added once (low wave)
        asm volatile("s_nop 3" : "+v"(acc));          // VALU init -> MFMA SrcC guard
        f32x4 ne = {0, 0, 0, 0};
        #pragma unroll 4
        for (int kt = 0; kt < 16; ++kt) {
            bf16x8 bh  = *(const bf16x8*)(qfh + bbW + kt * 64);
            bf16x8 bl  = *(const bf16x8*)(qfl + bbW + kt * 64);
            bf16x8 ch  = *(const bf16x8*)(qch + bbW + kt * 64);
            bf16x8 a0h = *(const bf16x8*)ph0; ph0 += 32;   // L2-cached (32x reuse/XCD)
            bf16x8 a0l = *(const bf16x8*)pl0; pl0 += 32;
            bf16x8 e0  = *(const bf16x8*)pe;  pe  += 32;
            acc = mfma_plain(a0h, bh, acc);
            acc = mfma_plain(a0h, bl, acc);
            acc = mfma_plain(a0l, bh, acc);
            ne  = mfma_plain(e0, ch, ne);
        }
        asm volatile("s_nop 7\n\ts_nop 7" : "+v"(acc), "+v"(ne));

        // ---- cross-wave K reduction (high waves publish, low waves sum) ----
        if (khalf) {
            #pragma unroll
            for (int r = 0; r < 4; ++r) {
                scA[wlow][lk * 4 + r][l16] = acc[r];
                scN[wlow][lk * 4 + r][l16] = ne[r];
            }
        }
        __syncthreads();
        if (!khalf) {
            #pragma unroll
            for (int r = 0; r < 4; ++r) {
                acc[r] += scA[wlow][lk * 4 + r][l16];
                eg[r]   = ne[r] + scN[wlow][lk * 4 + r][l16];
            }
            #pragma unroll
            for (int r = 0; r < 4; ++r)
                scA[wlow][lk * 4 + r][l16] = acc[r];     // final G for epilogue
        }

        if (!khalf) {
            // ---- LSTM update: thread owns (row R0+row_l, col); same-wave LDS ----
            f32x4 g4 = *(const f32x4*)&scA[wlow][row_l][jj * 4];   // f,i,c,o
            int row = R0 + row_l;
            float ff = sigmf(g4[0] + bf_r);
            float ii = sigmf(g4[1] + bi_r);
            float cv = tanhf (g4[2] + bc_r);
            float oo = sigmf(g4[3] + bo_r);
            float h1 = ff * hreg + ii * cv;
            hreg = h1;
            float y = oo * tanhf(h1);
            unsigned short hh = f2bf(h1);
            nxt_hi[row * UNITS + col] = hh;
            nxt_lo[row * UNITS + col] = f2bf(h1 - bf2f(hh));
            store_f32_nt(out + ((size_t)row * SEQ + t) * UNITS + col, y);
        } else {
            // ---- high waves: produce ebuf[(t+2)%3] = bf16(E[x[:,t+2]]) ----
            int q = tid - 512;
            if (q < 64) {
                int tt2 = (t + 2 < SEQ) ? t + 2 : SEQ - 1;
                int tok = x[(wg >> 1) * SEQ + tt2];
                const float* ps = E + (size_t)tok * UNITS + (wg & 1) * 512 + q * 8;
                *(bf16x8*)(eb + ((t + 2) % 3) * EBS + (wg >> 1) * UNITS
                           + (wg & 1) * 512 + q * 8) = cvt8(ps);
            }
        }
        // swap h buffers
        { unsigned short* tp;
          tp = cur_hi; cur_hi = nxt_hi; nxt_hi = tp;
          tp = cur_lo; cur_lo = nxt_lo; nxt_lo = tp; }

        if (t < SEQ - 1)
            grid_barrier((unsigned)(t + 2), wg, tid, grp, local,
                         xarr, garr, grel, xlead, xrel);
        else
            __syncthreads();
    }
}

extern "C" void kernel_launch(void* const* d_in, const int* in_sizes, int n_in,
                              void* d_out, int out_size, void* d_ws, size_t ws_size,
                              hipStream_t stream)
{
    const int*   x    = (const int*)d_in[0];
    const float* E    = (const float*)d_in[1];
    const float* Wh   = (const float*)d_in[2];
    const float* bvec = (const float*)d_in[3];
    const float* Wf   = (const float*)d_in[4];
    const float* bfv  = (const float*)d_in[5];
    const float* Wi   = (const float*)d_in[6];
    const float* biv  = (const float*)d_in[7];
    const float* Wc   = (const float*)d_in[8];
    const float* bcv  = (const float*)d_in[9];
    const float* Wo   = (const float*)d_in[10];
    const float* bov  = (const float*)d_in[11];
    float* out = (float*)d_out;

    // ---- workspace: [flags 32KB][h0 512KB][h1 512KB][ebuf 768KB] ≈ 1.8 MB ----
    char* w = (char*)d_ws;
    unsigned* xarr  = (unsigned*)(w);                       // 256 slots x 64B
    unsigned* garr  = (unsigned*)(w + 16384);               // 8 slots x 64B
    unsigned* grel  = (unsigned*)(w + 16384 + 512);         // 1 slot
    unsigned* xrel  = (unsigned*)(w + 16384 + 1024);        // 8 slots x 64B (phys XCD)
    unsigned* xlead = (unsigned*)(w + 16384 + 1536);        // 8 slots x 64B (election)
    const size_t FLG = 32768;
    const size_t HP  = (size_t)BATCH * UNITS * 2;           // 256 KB h plane
    unsigned short* hhi0 = (unsigned short*)(w + FLG);
    unsigned short* hlo0 = (unsigned short*)(w + FLG + HP);
    unsigned short* hhi1 = (unsigned short*)(w + FLG + 2 * HP);
    unsigned short* hlo1 = (unsigned short*)(w + FLG + 3 * HP);
    unsigned short* eb   = (unsigned short*)(w + FLG + 4 * HP);   // 3 x 256 KB
    // zero flags + h buf0 (buf1 fully written at t=0; ebuf fully written pre-use)
    hipMemsetAsync(w, 0, FLG + 2 * HP, stream);

    void* args[] = {
        (void*)&x, (void*)&E, (void*)&Wh, (void*)&bvec,
        (void*)&Wf, (void*)&Wi, (void*)&Wc, (void*)&Wo,
        (void*)&bfv, (void*)&biv, (void*)&bcv, (void*)&bov,
        (void*)&xarr, (void*)&garr, (void*)&grel, (void*)&xlead, (void*)&xrel,
        (void*)&hhi0, (void*)&hlo0, (void*)&hhi1, (void*)&hlo1,
        (void*)&eb, (void*)&out
    };
    hipLaunchCooperativeKernel(reinterpret_cast<void*>(lstm_all),
                               dim3(NWG), dim3(NTHR), args, 0, stream);
}

// Round 15
// 13941.188 us; speedup vs baseline: 1.2264x; 1.2264x over previous
//
#include <hip/hip_runtime.h>
#include <hip/hip_bf16.h>

#define UNITS 1024
#define BATCH 128
#define SEQ   512
#define NWG   256
#define NTHR  1024

typedef short bf16x8 __attribute__((ext_vector_type(8)));
typedef float f32x4  __attribute__((ext_vector_type(4)));

// ---- fp32 <-> bf16 split helpers (RNE) ----
__device__ __forceinline__ unsigned short f2bf(float v) {
    union { float f; unsigned u; } x; x.f = v;
    unsigned r = x.u + 0x7fffu + ((x.u >> 16) & 1u);
    return (unsigned short)(r >> 16);
}
__device__ __forceinline__ float bf2f(unsigned short s) {
    union { unsigned u; float f; } x; x.u = ((unsigned)s) << 16;
    return x.f;
}
__device__ __forceinline__ float sigmf(float v) { return 1.0f / (1.0f + expf(-v)); }

// A: lane holds A[row=l&15][k=8*(l>>4)+j]; B: B[k=8*(l>>4)+j][col=l&15];
// D: D[row=4*(l>>4)+r][col=l&15]
__device__ __forceinline__ f32x4 mfma_plain(bf16x8 a, bf16x8 b, f32x4 c) {
    asm("v_mfma_f32_16x16x32_bf16 %0, %1, %2, %0" : "+v"(c) : "v"(a), "v"(b));
    return c;
}
// s_nop fused into the SAME asm: guaranteed wait states between a preceding VALU
// write of a/b/c and the MFMA read (hazard recognizer can't see inline asm).
__device__ __forceinline__ f32x4 mfma_guard(bf16x8 a, bf16x8 b, f32x4 c) {
    asm("s_nop 3\n\tv_mfma_f32_16x16x32_bf16 %0, %1, %2, %0" : "+v"(c) : "v"(a), "v"(b));
    return c;
}

// 8 consecutive f32 -> bf16x8 via v_cvt_pk_bf16_f32 (VALU)
__device__ __forceinline__ bf16x8 cvt8(const float* p) {
    float4 f0 = *(const float4*)p;
    float4 f1 = *(const float4*)(p + 4);
    union { unsigned u[4]; bf16x8 v; } r;
    asm("v_cvt_pk_bf16_f32 %0, %1, %2" : "=v"(r.u[0]) : "v"(f0.x), "v"(f0.y));
    asm("v_cvt_pk_bf16_f32 %0, %1, %2" : "=v"(r.u[1]) : "v"(f0.z), "v"(f0.w));
    asm("v_cvt_pk_bf16_f32 %0, %1, %2" : "=v"(r.u[2]) : "v"(f1.x), "v"(f1.y));
    asm("v_cvt_pk_bf16_f32 %0, %1, %2" : "=v"(r.u[3]) : "v"(f1.z), "v"(f1.w));
    return r.v;
}

// non-temporal f32 store: out is never re-read -> don't let it evict E from LLC
__device__ __forceinline__ void store_f32_nt(float* p, float v) {
    asm volatile("global_store_dword %0, %1, off nt" :: "v"(p), "v"(v) : "memory");
}

__device__ __forceinline__ void flag_store(unsigned* p, unsigned v) {
    __hip_atomic_store(p, v, __ATOMIC_RELAXED, __HIP_MEMORY_SCOPE_AGENT);
}
__device__ __forceinline__ unsigned flag_load(const unsigned* p) {
    return __hip_atomic_load(p, __ATOMIC_RELAXED, __HIP_MEMORY_SCOPE_AGENT);
}

// Hierarchical barrier with DEDUP'D cache maintenance:
//   arrive tree (all 256 WGs drained to their L2s) -> aarr
//   ONE elected leader per PHYSICAL XCD: release fence (wbl2: that L2's dirty
//   lines -> LLC, covers all sibling WGs' stores) -> xwb ; wg0 collects -> grel
//   leader: buffer_inv sc1 (L2+L1) -> xrel ; others: buffer_inv sc0 (own L1)
// Replaces 32 wbl2-sweeps per XCD per step with 1.
__device__ __forceinline__ void grid_barrier(unsigned tgt, int wg, int tid, int grp, int local,
                                             unsigned* xarr, unsigned* garr,
                                             unsigned* aarr, unsigned* xlead,
                                             unsigned* xwb, unsigned* grel,
                                             unsigned* xrel)
{
    __syncthreads();                          // all waves' stores vmcnt-acked into L2
    if (tid == 0) {
        asm volatile("s_waitcnt vmcnt(0)" ::: "memory");
        flag_store(&xarr[wg * 16], tgt);      // arrive (no per-WG fence!)
    }
    if (local == 0) {                         // logical-group fan-in (32 par. pollers)
        if (tid < 32)
            while (flag_load(&xarr[(grp + 8 * tid) * 16]) < tgt)
                __builtin_amdgcn_s_sleep(1);
        __syncthreads();
        if (tid == 0) flag_store(&garr[grp * 16], tgt);
    }
    if (wg == 0) {                            // global fan-in -> all-arrived
        if (tid < 8)
            while (flag_load(&garr[tid * 16]) < tgt)
                __builtin_amdgcn_s_sleep(1);
        __syncthreads();
        if (tid == 0) flag_store(aarr, tgt);
    }
    // ---- election + single wbl2 per physical XCD ----
    unsigned px = 0; bool lead = false;
    if (tid == 0) {
        asm volatile("s_getreg_b32 %0, hwreg(HW_REG_XCC_ID)" : "=s"(px));
        px &= 7;
        unsigned pre = __hip_atomic_fetch_max(&xlead[px * 16], tgt,
                                              __ATOMIC_RELAXED, __HIP_MEMORY_SCOPE_AGENT);
        lead = (pre < tgt);
        if (lead) {
            while (flag_load(aarr) < tgt) __builtin_amdgcn_s_sleep(1);
            __builtin_amdgcn_fence(__ATOMIC_RELEASE, "agent");  // wbl2: this L2 -> LLC
            flag_store(&xwb[px * 16], tgt);
        }
    }
    if (wg == 0) {                            // collect 8 writeback-done flags
        if (tid < 8)
            while (flag_load(&xwb[tid * 16]) < tgt)
                __builtin_amdgcn_s_sleep(1);
        __syncthreads();
        if (tid == 0) flag_store(grel, tgt);  // all XCD L2s flushed to LLC
    }
    if (tid == 0) {
        if (lead) {
            while (flag_load(grel) < tgt) __builtin_amdgcn_s_sleep(1);
            asm volatile("buffer_inv sc1\n\ts_waitcnt vmcnt(0)" ::: "memory"); // L1+L2
            flag_store(&xrel[px * 16], tgt);
        } else {
            while (flag_load(&xrel[px * 16]) < tgt) __builtin_amdgcn_s_sleep(1);
            asm volatile("buffer_inv sc0\n\ts_waitcnt vmcnt(0)" ::: "memory"); // own L1
        }
    }
    __syncthreads();
}

// ============ single persistent kernel, 256 WGs x 1024 thr (16 waves/CU) ============
// Each WG owns 4 h-cols = 16 gate-cols (gate-interleaved: cc = 4*hcol + g).
// K-split: wave w<8 = rows w*16..+15, K[0,512); wave w+8 = same rows, K[512,1024).
// Per step: acc = h@Wfused (+eg in low wave), ne = ebuf@Wcat_hi; partials reduced
// via LDS; low waves do LSTM epilogue; high waves produce ebuf[(t+2)%3].
__global__ void __launch_bounds__(1024, 1)
lstm_all(const int* __restrict__ x, const float* __restrict__ E,
         const float* __restrict__ Wh, const float* __restrict__ bvec,
         const float* __restrict__ Wf, const float* __restrict__ Wi,
         const float* __restrict__ Wc, const float* __restrict__ Wo,
         const float* __restrict__ bfv, const float* __restrict__ biv,
         const float* __restrict__ bcv, const float* __restrict__ bov,
         unsigned* __restrict__ xarr, unsigned* __restrict__ garr,
         unsigned* __restrict__ aarr, unsigned* __restrict__ xlead,
         unsigned* __restrict__ xwb, unsigned* __restrict__ grel,
         unsigned* __restrict__ xrel,
         unsigned short* __restrict__ h_hi0, unsigned short* __restrict__ h_lo0,
         unsigned short* __restrict__ h_hi1, unsigned short* __restrict__ h_lo1,
         unsigned short* __restrict__ eb,    // 3 slots of [128][1024] bf16
         float* __restrict__ out)
{
    __shared__ unsigned short lwf_h[16 * 1032];   // 33 KB Wfused tile hi (2064 B rows)
    __shared__ unsigned short lwf_l[16 * 1032];   // 33 KB Wfused tile lo
    __shared__ unsigned short lwc_h[16 * 1032];   // 33 KB Wcat tile hi
    __shared__ unsigned short lwc_l[16 * 1032];   // 33 KB Wcat tile lo (S3 only)
    __shared__ __align__(16) float scA[8][16][20];  // 10 KB acc partials / G epilogue
    __shared__ __align__(16) float scN[8][16][20];  // 10 KB ne partials
    __shared__ float bgl[16];

    const int wg = blockIdx.x, tid = threadIdx.x;
    const int wave = tid >> 6, lane = tid & 63;
    const int l16 = lane & 15, lk = lane >> 4;
    const int wlow = wave & 7;               // row-group
    const int khalf = wave >> 3;             // 0 = K[0,512), 1 = K[512,1024)

    // logical column ownership (also the barrier-tree grouping)
    const int grp = wg & 7, local = wg >> 3;
    const int hcb = grp * 128 + local * 4;   // 4 h-cols
    const int gcb = hcb * 4;                 // 16 gate-cols

    const int kh   = khalf * 512;
    const int bbW  = l16 * 2064 + kh * 2 + lk * 16;  // weight-LDS byte offset
    const int bbW0 = l16 * 2064 + lk * 16;           // full-K variant (S3)
    const char* qfh = (const char*)lwf_h;
    const char* qfl = (const char*)lwf_l;
    const char* qch = (const char*)lwc_h;
    const char* qcl = (const char*)lwc_l;

    // ======== S1: build Wcat^T dual tile from f32 gate weights ========
    for (int idx = tid; idx < 16 * 1024; idx += NTHR) {
        int i = idx >> 10, k = idx & 1023;
        int cc = gcb + i;
        int j = cc >> 2, g = cc & 3;
        const float* W = (g == 0) ? Wf : (g == 1) ? Wi : (g == 2) ? Wc : Wo;
        float v = W[k * UNITS + j];
        unsigned short hi = f2bf(v);
        lwc_h[i * 1032 + k] = hi;
        lwc_l[i * 1032 + k] = f2bf(v - bf2f(hi));
    }
    __syncthreads();

    // ======== S2: bgl[i] = sum_k bvec[k] * Wcat[k][gcb+i] ========
    {
        int i = tid >> 6, seg = tid & 63;    // 16 cols x 64 segments of 16
        float s = 0.0f;
        #pragma unroll 4
        for (int k = seg * 16; k < seg * 16 + 16; ++k)
            s += bvec[k] * (bf2f(lwc_h[i * 1032 + k]) + bf2f(lwc_l[i * 1032 + k]));
        ((float*)scA)[i * 64 + seg] = s;
    }
    __syncthreads();
    if (tid < 16) {
        float s = 0.0f;
        #pragma unroll
        for (int q = 0; q < 64; ++q) s += ((float*)scA)[tid * 64 + q];
        bgl[tid] = s;
    }
    __syncthreads();

    // ======== S3: Wfused tile = Wh @ Wcat_tile (dual x dual, 3 products) ========
    for (int rt = wave; rt < 64; rt += 16) {
        const int kb = rt * 16;
        const float* pa = Wh + (size_t)(kb + l16) * UNITS + lk * 8;
        f32x4 acc = {0, 0, 0, 0};
        for (int kt = 0; kt < 32; ++kt) {
            float4 w0 = *(const float4*)pa;
            float4 w1 = *(const float4*)(pa + 4);
            pa += 32;
            union { unsigned short u[8]; bf16x8 v; } ah, al;
            float wv[8] = {w0.x, w0.y, w0.z, w0.w, w1.x, w1.y, w1.z, w1.w};
            #pragma unroll
            for (int j = 0; j < 8; ++j) {
                ah.u[j] = f2bf(wv[j]);
                al.u[j] = f2bf(wv[j] - bf2f(ah.u[j]));
            }
            bf16x8 bh = *(const bf16x8*)(qch + bbW0 + kt * 64);
            bf16x8 bl = *(const bf16x8*)(qcl + bbW0 + kt * 64);
            acc = mfma_guard(ah.v, bh, acc);
            acc = mfma_guard(ah.v, bl, acc);
            acc = mfma_guard(al.v, bh, acc);
        }
        asm volatile("s_nop 7\n\ts_nop 7" : "+v"(acc));
        #pragma unroll
        for (int r = 0; r < 4; ++r) {
            float v = acc[r];
            unsigned short hi = f2bf(v);
            int o = l16 * 1032 + kb + 4 * lk + r;
            lwf_h[o] = hi;
            lwf_l[o] = f2bf(v - bf2f(hi));
        }
    }
    __syncthreads();

    // ---- per-thread epilogue statics ----
    const int row_l = lane >> 2;             // 0..15
    const int jj    = lane & 3;              // h-col within WG
    const int col   = hcb + jj;
    const float bf_r = bfv[col] + bgl[4 * jj + 0];
    const float bi_r = biv[col] + bgl[4 * jj + 1];
    const float bc_r = bcv[col] + bgl[4 * jj + 2];
    const float bo_r = bov[col] + bgl[4 * jj + 3];
    float hreg = 0.0f;
    const int R0 = wlow * 16;

    unsigned short* cur_hi = h_hi0; unsigned short* cur_lo = h_lo0;
    unsigned short* nxt_hi = h_hi1; unsigned short* nxt_lo = h_lo1;
    const size_t EBS = (size_t)BATCH * UNITS;     // one ebuf slot

    // ---- prologue: produce ebuf slot0 (tokens t=0) and slot1 (tokens t=1) ----
    {
        int q = tid;
        if (q < 64) {
            int tok = x[(wg >> 1) * SEQ + 0];
            const float* ps = E + (size_t)tok * UNITS + (wg & 1) * 512 + q * 8;
            *(bf16x8*)(eb + (wg >> 1) * UNITS + (wg & 1) * 512 + q * 8) = cvt8(ps);
        } else if (q < 128) {
            int qq = q - 64;
            int tok = x[(wg >> 1) * SEQ + 1];
            const float* ps = E + (size_t)tok * UNITS + (wg & 1) * 512 + qq * 8;
            *(bf16x8*)(eb + EBS + (wg >> 1) * UNITS + (wg & 1) * 512 + qq * 8) = cvt8(ps);
        }
    }
    grid_barrier(1u, wg, tid, grp, local, xarr, garr, aarr, xlead, xwb, grel, xrel);

    // ---- prologue ne: eg for t=0 from ebuf slot0 (K-split, LDS reduce) ----
    f32x4 eg = {0, 0, 0, 0};
    {
        const unsigned short* pe = eb + (R0 + l16) * UNITS + kh + lk * 8;
        f32x4 ne = {0, 0, 0, 0};
        #pragma unroll 4
        for (int kt = 0; kt < 16; ++kt) {
            bf16x8 e0 = *(const bf16x8*)pe; pe += 32;
            bf16x8 ch = *(const bf16x8*)(qch + bbW + kt * 64);
            ne = mfma_plain(e0, ch, ne);
        }
        asm volatile("s_nop 7\n\ts_nop 7" : "+v"(ne));
        if (khalf) {
            #pragma unroll
            for (int r = 0; r < 4; ++r) scN[wlow][lk * 4 + r][l16] = ne[r];
        }
        __syncthreads();
        if (!khalf) {
            #pragma unroll
            for (int r = 0; r < 4; ++r) eg[r] = ne[r] + scN[wlow][lk * 4 + r][l16];
        }
    }

    #pragma unroll 1
    for (int t = 0; t < SEQ; ++t) {
        const unsigned short* ebr = eb + ((t + 1) % 3) * EBS;   // tokens t+1
        const unsigned short* pe  = ebr + (R0 + l16) * UNITS + kh + lk * 8;
        const unsigned short* ph0 = cur_hi + (R0 + l16) * UNITS + kh + lk * 8;
        const unsigned short* pl0 = cur_lo + (R0 + l16) * UNITS + kh + lk * 8;

        f32x4 acc = khalf ? f32x4{0, 0, 0, 0} : eg;   // eg added once (low wave)
        asm volatile("s_nop 3" : "+v"(acc));          // VALU init -> MFMA SrcC guard
        f32x4 ne = {0, 0, 0, 0};
        #pragma unroll 4
        for (int kt = 0; kt < 16; ++kt) {
            bf16x8 bh  = *(const bf16x8*)(qfh + bbW + kt * 64);
            bf16x8 bl  = *(const bf16x8*)(qfl + bbW + kt * 64);
            bf16x8 ch  = *(const bf16x8*)(qch + bbW + kt * 64);
            bf16x8 a0h = *(const bf16x8*)ph0; ph0 += 32;   // L2-cached (32x reuse/XCD)
            bf16x8 a0l = *(const bf16x8*)pl0; pl0 += 32;
            bf16x8 e0  = *(const bf16x8*)pe;  pe  += 32;
            acc = mfma_plain(a0h, bh, acc);
            acc = mfma_plain(a0h, bl, acc);
            acc = mfma_plain(a0l, bh, acc);
            ne  = mfma_plain(e0, ch, ne);
        }
        asm volatile("s_nop 7\n\ts_nop 7" : "+v"(acc), "+v"(ne));

        // ---- cross-wave K reduction (high waves publish, low waves sum) ----
        if (khalf) {
            #pragma unroll
            for (int r = 0; r < 4; ++r) {
                scA[wlow][lk * 4 + r][l16] = acc[r];
                scN[wlow][lk * 4 + r][l16] = ne[r];
            }
        }
        __syncthreads();
        if (!khalf) {
            #pragma unroll
            for (int r = 0; r < 4; ++r) {
                acc[r] += scA[wlow][lk * 4 + r][l16];
                eg[r]   = ne[r] + scN[wlow][lk * 4 + r][l16];
            }
            #pragma unroll
            for (int r = 0; r < 4; ++r)
                scA[wlow][lk * 4 + r][l16] = acc[r];     // final G for epilogue
        }

        if (!khalf) {
            // ---- LSTM update: thread owns (row R0+row_l, col); same-wave LDS ----
            f32x4 g4 = *(const f32x4*)&scA[wlow][row_l][jj * 4];   // f,i,c,o
            int row = R0 + row_l;
            float ff = sigmf(g4[0] + bf_r);
            float ii = sigmf(g4[1] + bi_r);
            float cv = tanhf (g4[2] + bc_r);
            float oo = sigmf(g4[3] + bo_r);
            float h1 = ff * hreg + ii * cv;
            hreg = h1;
            float y = oo * tanhf(h1);
            unsigned short hh = f2bf(h1);
            nxt_hi[row * UNITS + col] = hh;
            nxt_lo[row * UNITS + col] = f2bf(h1 - bf2f(hh));
            store_f32_nt(out + ((size_t)row * SEQ + t) * UNITS + col, y);
        } else {
            // ---- high waves: produce ebuf[(t+2)%3] = bf16(E[x[:,t+2]]) ----
            int q = tid - 512;
            if (q < 64) {
                int tt2 = (t + 2 < SEQ) ? t + 2 : SEQ - 1;
                int tok = x[(wg >> 1) * SEQ + tt2];
                const float* ps = E + (size_t)tok * UNITS + (wg & 1) * 512 + q * 8;
                *(bf16x8*)(eb + ((t + 2) % 3) * EBS + (wg >> 1) * UNITS
                           + (wg & 1) * 512 + q * 8) = cvt8(ps);
            }
        }
        // swap h buffers
        { unsigned short* tp;
          tp = cur_hi; cur_hi = nxt_hi; nxt_hi = tp;
          tp = cur_lo; cur_lo = nxt_lo; nxt_lo = tp; }

        if (t < SEQ - 1)
            grid_barrier((unsigned)(t + 2), wg, tid, grp, local,
                         xarr, garr, aarr, xlead, xwb, grel, xrel);
        else
            __syncthreads();
    }
}

extern "C" void kernel_launch(void* const* d_in, const int* in_sizes, int n_in,
                              void* d_out, int out_size, void* d_ws, size_t ws_size,
                              hipStream_t stream)
{
    const int*   x    = (const int*)d_in[0];
    const float* E    = (const float*)d_in[1];
    const float* Wh   = (const float*)d_in[2];
    const float* bvec = (const float*)d_in[3];
    const float* Wf   = (const float*)d_in[4];
    const float* bfv  = (const float*)d_in[5];
    const float* Wi   = (const float*)d_in[6];
    const float* biv  = (const float*)d_in[7];
    const float* Wc   = (const float*)d_in[8];
    const float* bcv  = (const float*)d_in[9];
    const float* Wo   = (const float*)d_in[10];
    const float* bov  = (const float*)d_in[11];
    float* out = (float*)d_out;

    // ---- workspace: [flags 32KB][h0 512KB][h1 512KB][ebuf 768KB] ≈ 1.8 MB ----
    char* w = (char*)d_ws;
    unsigned* xarr  = (unsigned*)(w);                       // 256 slots x 64B
    unsigned* garr  = (unsigned*)(w + 16384);               // 8 slots x 64B
    unsigned* aarr  = (unsigned*)(w + 16384 + 512);         // 1 slot (all-arrived)
    unsigned* grel  = (unsigned*)(w + 16384 + 576);         // 1 slot (all-flushed)
    unsigned* xlead = (unsigned*)(w + 16384 + 1024);        // 8 slots x 64B (election)
    unsigned* xwb   = (unsigned*)(w + 16384 + 1536);        // 8 slots x 64B (wb done)
    unsigned* xrel  = (unsigned*)(w + 16384 + 2048);        // 8 slots x 64B (inv done)
    const size_t FLG = 32768;
    const size_t HP  = (size_t)BATCH * UNITS * 2;           // 256 KB h plane
    unsigned short* hhi0 = (unsigned short*)(w + FLG);
    unsigned short* hlo0 = (unsigned short*)(w + FLG + HP);
    unsigned short* hhi1 = (unsigned short*)(w + FLG + 2 * HP);
    unsigned short* hlo1 = (unsigned short*)(w + FLG + 3 * HP);
    unsigned short* eb   = (unsigned short*)(w + FLG + 4 * HP);   // 3 x 256 KB
    // zero flags + h buf0 (buf1 fully written at t=0; ebuf fully written pre-use)
    hipMemsetAsync(w, 0, FLG + 2 * HP, stream);

    void* args[] = {
        (void*)&x, (void*)&E, (void*)&Wh, (void*)&bvec,
        (void*)&Wf, (void*)&Wi, (void*)&Wc, (void*)&Wo,
        (void*)&bfv, (void*)&biv, (void*)&bcv, (void*)&bov,
        (void*)&xarr, (void*)&garr, (void*)&aarr, (void*)&xlead,
        (void*)&xwb, (void*)&grel, (void*)&xrel,
        (void*)&hhi0, (void*)&hlo0, (void*)&hhi1, (void*)&hlo1,
        (void*)&eb, (void*)&out
    };
    hipLaunchCooperativeKernel(reinterpret_cast<void*>(lstm_all),
                               dim3(NWG), dim3(NTHR), args, 0, stream);
}